// Round 8
// baseline (103.997 us; speedup 1.0000x reference)
//
#include <hip/hip_runtime.h>
#include <hip/hip_bf16.h>

// Weight-only int4 GEMM (M=2048, N=4096, K=4096, G=128):
//   1) cvt_a   : fp32 A -> bf16 Ab[M][K] in d_ws (only prepass left)
//   2) gemm_fq : R5 pipelined bf16 GEMM (BM=256 x BN=128, BK=64, 8 waves of
//        64x64, mfma_f32_32x32x16_bf16, ONE barrier/K-tile, 3-deep LDS ring)
//        with W-dequant FUSED into B staging: per lane 8 packed int32 ->
//        16 bf16 -> 2 swizzled ds_write_b128. A stays on global_load_lds.
//        vmem/tile = Bp x2 + SZ x1 + A-gload x4; mid-wait vmcnt(4) leaves
//        exactly the 4 A-gloads of tile t+2 in flight.

using bf16x8 = __attribute__((ext_vector_type(8))) short;
using f32x16 = __attribute__((ext_vector_type(16))) float;

#define KK 4096
#define NN 4096
#define NT (KK / 64)

static __device__ __forceinline__ short f2bf(float f) {
    __hip_bfloat16 h = __float2bfloat16(f);
    return __builtin_bit_cast(short, h);
}

#define GLDS16(gptr, lptr) __builtin_amdgcn_global_load_lds( \
    (const __attribute__((address_space(1))) void*)(gptr),   \
    (__attribute__((address_space(3))) void*)(lptr), 16, 0, 0)

#define MFMA32 __builtin_amdgcn_mfma_f32_32x32x16_bf16
#define SBAR() __builtin_amdgcn_sched_barrier(0)

static __device__ __forceinline__ bf16x8 dq8(int4 p, float s, float zs) {
    bf16x8 r;
    int v[4] = {p.x, p.y, p.z, p.w};
    #pragma unroll
    for (int j = 0; j < 4; ++j) {
        r[2 * j]     = f2bf((float)((v[j] >> 4) & 0xF) * s + zs); // even k
        r[2 * j + 1] = f2bf((float)(v[j] & 0xF) * s + zs);        // odd k
    }
    return r;
}

// ---------------- pre-pass: A fp32 -> bf16 ----------------
__global__ __launch_bounds__(256) void cvt_a(
    const float* __restrict__ A, short* __restrict__ Ab)
{
    const int idx = blockIdx.x * 256 + threadIdx.x;
    const float4* s = (const float4*)(A + (size_t)idx * 8);
    float4 u = s[0], v = s[1];
    bf16x8 r;
    r[0] = f2bf(u.x); r[1] = f2bf(u.y); r[2] = f2bf(u.z); r[3] = f2bf(u.w);
    r[4] = f2bf(v.x); r[5] = f2bf(v.y); r[6] = f2bf(v.z); r[7] = f2bf(v.w);
    *(bf16x8*)&Ab[(size_t)idx * 8] = r;
}

// ---------------- main pipelined GEMM, fused W-dequant ----------------
// LDS(row, chunk c) holds global(row, c ^ (row&7)); chunks are 16B.
__global__ __launch_bounds__(512, 2) void gemm_fq(
    const short* __restrict__ Ab, const int* __restrict__ W,
    const float* __restrict__ SZ, float* __restrict__ C)
{
    __shared__ short sA[3 * 256 * 64];   // 96 KiB
    __shared__ short sB[3 * 128 * 64];   // 48 KiB

    const int tid  = threadIdx.x;
    const int lane = tid & 63;
    const int wave = tid >> 6;           // 0..7
    const int wm   = wave >> 1;          // m-offset wm*64 (0..3)
    const int wn   = wave & 1;           // n-offset wn*64
    const int bm   = blockIdx.y * 256;
    const int bn   = blockIdx.x * 128;

    // A staging via gload_lds: wave fills 8 rows x 8 chunks linearly in LDS;
    // global source pre-swizzled: row += lane>>3, chunk (lane&7)^(lane>>3)
    const int sl = lane >> 3;
    const int sc = (lane & 7) ^ sl;
    const short* aSt = Ab + (size_t)(bm + wave * 32 + sl) * KK + sc * 8;

    // B staging: reg-staged packed int4 + dequant.
    // Per lane: tile-row brow = wave*16 + (lane>>2); 8 int32 = 16 k-elems
    // (k-local [bl4*16, bl4*16+16)); two swizzled ds_write_b128.
    const int brow = wave * 16 + (lane >> 2);
    const int bl4  = lane & 3;
    const int* wSt = W + (size_t)(bn + brow) * (KK / 2) + bl4 * 8;
    const float* szp = SZ + (size_t)(bn + brow) * 2;
    const int bw0 = brow * 64 + (((bl4 * 2))     ^ (brow & 7)) * 8;
    const int bw1 = brow * 64 + (((bl4 * 2) | 1) ^ (brow & 7)) * 8;

    // 32x32x16 fragment reads: row = base + (lane&31);
    // logical chunk = slice*2 + (lane>>5); phys = logical ^ (lane&7)
    const int l31 = lane & 31;
    const int lx  = lane >> 5;
    const int l7  = lane & 7;
    const int px0 = ((0 + lx) ^ l7) * 8;   // k-slice 0
    const int px1 = ((2 + lx) ^ l7) * 8;   // k-slice 1
    const int px2 = ((4 + lx) ^ l7) * 8;   // k-slice 2
    const int px3 = ((6 + lx) ^ l7) * 8;   // k-slice 3
    const int aRd = (wm * 64 + l31) * 64;
    const int bRd = (wn * 64 + l31) * 64;

    f32x16 acc00 = {}, acc01 = {}, acc10 = {}, acc11 = {};
    bf16x8 pA00, pA01, pA10, pA11, pB00, pB01, pB10, pB11;  // phase-0 frags
    bf16x8 qA00, qA01, qA10, qA11, qB00, qB01, qB10, qB11;  // phase-1 frags

    // ---- prologue: stage K-tiles 0 and 1 ----
    // vmem issue order: Bp0 x2, SZ0, Bp1 x2, A0-gload x4, A1-gload x4
    int4 b00p = *(const int4*)(wSt + 0);
    int4 b01p = *(const int4*)(wSt + 4);
    float2 sz0 = *(const float2*)(szp);                  // group 0
    int4 b10p = *(const int4*)(wSt + 32);
    int4 b11p = *(const int4*)(wSt + 36);
    #pragma unroll
    for (int l = 0; l < 4; ++l)
        GLDS16(aSt + (size_t)l * 8 * KK,      &sA[(wave * 32 + l * 8) * 64]);
    #pragma unroll
    for (int l = 0; l < 4; ++l)
        GLDS16(aSt + (size_t)l * 8 * KK + 64, &sA[16384 + (wave * 32 + l * 8) * 64]);
    {
        const float s = sz0.x, zs = sz0.y - 8.0f * sz0.x;
        *(bf16x8*)&sB[bw0]        = dq8(b00p, s, zs);   // tile 0
        *(bf16x8*)&sB[bw1]        = dq8(b01p, s, zs);
        *(bf16x8*)&sB[8192 + bw0] = dq8(b10p, s, zs);   // tile 1
        *(bf16x8*)&sB[8192 + bw1] = dq8(b11p, s, zs);
    }
    asm volatile("s_waitcnt vmcnt(4)" ::: "memory");   // A0 landed; A1 in flight
    asm volatile("s_waitcnt lgkmcnt(0)" ::: "memory"); // B writes done
    __builtin_amdgcn_s_barrier();

    // first p-set of tile 0 (slices 0,1)
    pA00 = *(const bf16x8*)&sA[aRd + px0];
    pA01 = *(const bf16x8*)&sA[aRd + px1];
    pA10 = *(const bf16x8*)&sA[aRd + 2048 + px0];
    pA11 = *(const bf16x8*)&sA[aRd + 2048 + px1];
    pB00 = *(const bf16x8*)&sB[bRd + px0];
    pB01 = *(const bf16x8*)&sB[bRd + px1];
    pB10 = *(const bf16x8*)&sB[bRd + 2048 + px0];
    pB11 = *(const bf16x8*)&sB[bRd + 2048 + px1];
    asm volatile("s_waitcnt lgkmcnt(0)" ::: "memory");
    SBAR();

    int cur = 0;
    for (int t = 0; t < NT; ++t) {
        const int nxt1 = (cur == 2) ? 0 : cur + 1;     // (t+1)%3
        const int nxt2 = (nxt1 == 2) ? 0 : nxt1 + 1;   // (t+2)%3
        const short* sAc = &sA[cur * 16384];
        const short* sBc = &sB[cur * 8192];
        const short* sA1 = &sA[nxt1 * 16384];
        const short* sB1 = &sB[nxt1 * 8192];
        short* sAn = &sA[nxt2 * 16384];
        short* sBn = &sB[nxt2 * 8192];
        const bool st = (t + 2 < NT);
        const int gk = (t + 2) * 64;

        // -- issue q-set frag reads (slices 2,3) + all staging for t+2 --
        qA00 = *(const bf16x8*)&sAc[aRd + px2];
        qA01 = *(const bf16x8*)&sAc[aRd + px3];
        qA10 = *(const bf16x8*)&sAc[aRd + 2048 + px2];
        qA11 = *(const bf16x8*)&sAc[aRd + 2048 + px3];
        qB00 = *(const bf16x8*)&sBc[bRd + px2];
        qB01 = *(const bf16x8*)&sBc[bRd + px3];
        qB10 = *(const bf16x8*)&sBc[bRd + 2048 + px2];
        qB11 = *(const bf16x8*)&sBc[bRd + 2048 + px3];
        int4 bp0, bp1; float2 szv;
        if (st) {
            bp0 = *(const int4*)(wSt + (gk >> 1));       // (t+2)*32
            bp1 = *(const int4*)(wSt + (gk >> 1) + 4);
            szv = *(const float2*)(szp + (size_t)((t + 2) >> 1) * NN * 2);
            GLDS16(aSt + (size_t)0 * 8 * KK + gk, sAn + (wave * 32 + 0) * 64);
            GLDS16(aSt + (size_t)1 * 8 * KK + gk, sAn + (wave * 32 + 8) * 64);
            GLDS16(aSt + (size_t)2 * 8 * KK + gk, sAn + (wave * 32 + 16) * 64);
            GLDS16(aSt + (size_t)3 * 8 * KK + gk, sAn + (wave * 32 + 24) * 64);
        }
        SBAR();

        // -- MFMA on p-set (overlaps the reads above) --
        __builtin_amdgcn_s_setprio(1);
        acc00 = MFMA32(pA00, pB00, acc00, 0, 0, 0);
        acc00 = MFMA32(pA01, pB01, acc00, 0, 0, 0);
        acc01 = MFMA32(pA00, pB10, acc01, 0, 0, 0);
        acc01 = MFMA32(pA01, pB11, acc01, 0, 0, 0);
        acc10 = MFMA32(pA10, pB00, acc10, 0, 0, 0);
        acc10 = MFMA32(pA11, pB01, acc10, 0, 0, 0);
        acc11 = MFMA32(pA10, pB10, acc11, 0, 0, 0);
        acc11 = MFMA32(pA11, pB11, acc11, 0, 0, 0);
        __builtin_amdgcn_s_setprio(0);

        // -- mid wait: Bp/SZ(t+2) + A(t+1) drained; A(t+2) stays in flight --
        if (st) {
            asm volatile("s_waitcnt vmcnt(4)" ::: "memory");
        } else {
            asm volatile("s_waitcnt vmcnt(0)" ::: "memory");
        }
        SBAR();
        if (st) {
            const float s = szv.x, zs = szv.y - 8.0f * szv.x;
            *(bf16x8*)&sBn[bw0] = dq8(bp0, s, zs);
            *(bf16x8*)&sBn[bw1] = dq8(bp1, s, zs);
        }
        asm volatile("s_waitcnt lgkmcnt(0)" ::: "memory");
        SBAR();
        __builtin_amdgcn_s_barrier();

        // -- issue next-tile p-set frag reads --
        if (t + 1 < NT) {
            pA00 = *(const bf16x8*)&sA1[aRd + px0];
            pA01 = *(const bf16x8*)&sA1[aRd + px1];
            pA10 = *(const bf16x8*)&sA1[aRd + 2048 + px0];
            pA11 = *(const bf16x8*)&sA1[aRd + 2048 + px1];
            pB00 = *(const bf16x8*)&sB1[bRd + px0];
            pB01 = *(const bf16x8*)&sB1[bRd + px1];
            pB10 = *(const bf16x8*)&sB1[bRd + 2048 + px0];
            pB11 = *(const bf16x8*)&sB1[bRd + 2048 + px1];
        }
        SBAR();

        // -- MFMA on q-set (overlaps the reads above) --
        __builtin_amdgcn_s_setprio(1);
        acc00 = MFMA32(qA00, qB00, acc00, 0, 0, 0);
        acc00 = MFMA32(qA01, qB01, acc00, 0, 0, 0);
        acc01 = MFMA32(qA00, qB10, acc01, 0, 0, 0);
        acc01 = MFMA32(qA01, qB11, acc01, 0, 0, 0);
        acc10 = MFMA32(qA10, qB00, acc10, 0, 0, 0);
        acc10 = MFMA32(qA11, qB01, acc10, 0, 0, 0);
        acc11 = MFMA32(qA10, qB10, acc11, 0, 0, 0);
        acc11 = MFMA32(qA11, qB11, acc11, 0, 0, 0);
        __builtin_amdgcn_s_setprio(0);

        asm volatile("s_waitcnt lgkmcnt(0)" ::: "memory");
        SBAR();

        cur = nxt1;
    }

    // ---- epilogue: 32x32 C/D layout: col = lane&31,
    //      row = (reg&3) + 8*(reg>>2) + 4*(lane>>5) ----
    {
        const int crow = lx * 4;
        float* Cp = C + (size_t)(bm + wm * 64) * NN + bn + wn * 64;
        #pragma unroll
        for (int m = 0; m < 2; ++m) {
            #pragma unroll
            for (int qr = 0; qr < 4; ++qr) {
                #pragma unroll
                for (int j = 0; j < 4; ++j) {
                    const int row = m * 32 + crow + j + 8 * qr;
                    float* dst = Cp + (size_t)row * NN + l31;
                    if (m == 0) {
                        dst[0]  = acc00[qr * 4 + j];
                        dst[32] = acc01[qr * 4 + j];
                    } else {
                        dst[0]  = acc10[qr * 4 + j];
                        dst[32] = acc11[qr * 4 + j];
                    }
                }
            }
        }
    }
}

// ---------------- fallback: round-1 fused kernel ----------------
using f32x4 = __attribute__((ext_vector_type(4))) float;
#define LDKF 72
__global__ __launch_bounds__(256) void wq4_gemm_fused(
    const float* __restrict__ A, const int* __restrict__ W,
    const float* __restrict__ SZ, float* __restrict__ C, int M)
{
    __shared__ short sA[128 * LDKF];
    __shared__ short sB[128 * LDKF];
    const int tid = threadIdx.x, lane = tid & 63, wave = tid >> 6;
    const int wr = (wave >> 1) << 6, wc = (wave & 1) << 6;
    const int bm = blockIdx.y * 128, bn = blockIdx.x * 128;
    const int ar = tid >> 2, ac = (tid & 3) << 4;
    const int br = tid >> 1, bh = (tid & 1) << 4;
    const float* Arow0 = A + (size_t)(bm + ar) * KK + ac;
    const float* Arow1 = A + (size_t)(bm + 64 + ar) * KK + ac;
    const int*   Wrow  = W + (size_t)(bn + br) * (KK / 2) + bh;
    const float* SZrow = SZ + (size_t)(bn + br) * 2;
    f32x4 acc[4][4] = {};
    for (int k0 = 0; k0 < KK; k0 += 64) {
        {
            const float4* s0 = (const float4*)(Arow0 + k0);
            const float4* s1 = (const float4*)(Arow1 + k0);
            float4 a0 = s0[0], a1 = s0[1], a2 = s0[2], a3 = s0[3];
            float4 b0 = s1[0], b1 = s1[1], b2 = s1[2], b3 = s1[3];
            auto cvt8 = [](float4 u, float4 v) -> bf16x8 {
                bf16x8 r;
                r[0] = f2bf(u.x); r[1] = f2bf(u.y); r[2] = f2bf(u.z); r[3] = f2bf(u.w);
                r[4] = f2bf(v.x); r[5] = f2bf(v.y); r[6] = f2bf(v.z); r[7] = f2bf(v.w);
                return r;
            };
            *(bf16x8*)&sA[ar * LDKF + ac]            = cvt8(a0, a1);
            *(bf16x8*)&sA[ar * LDKF + ac + 8]        = cvt8(a2, a3);
            *(bf16x8*)&sA[(64 + ar) * LDKF + ac]     = cvt8(b0, b1);
            *(bf16x8*)&sA[(64 + ar) * LDKF + ac + 8] = cvt8(b2, b3);
        }
        {
            const int g = k0 >> 7;
            const float2 sz = *(const float2*)(SZrow + (size_t)g * NN * 2);
            const float scale = sz.x, zs = sz.y - 8.0f * sz.x;
            const int4* src = (const int4*)(Wrow + (k0 >> 1));
            #pragma unroll
            for (int i = 0; i < 4; ++i) {
                int4 p = src[i];
                int vals[4] = {p.x, p.y, p.z, p.w};
                bf16x8 r;
                #pragma unroll
                for (int j = 0; j < 4; ++j) {
                    int v = vals[j];
                    r[2 * j]     = f2bf((float)((v >> 4) & 0xF) * scale + zs);
                    r[2 * j + 1] = f2bf((float)(v & 0xF) * scale + zs);
                }
                *(bf16x8*)&sB[br * LDKF + (bh << 1) + (i << 3)] = r;
            }
        }
        __syncthreads();
        #pragma unroll
        for (int ks = 0; ks < 2; ++ks) {
            const int col = (ks << 5) + ((lane >> 4) << 3);
            bf16x8 af[4], bfr[4];
            #pragma unroll
            for (int m = 0; m < 4; ++m)
                af[m] = *(const bf16x8*)&sA[(wr + m * 16 + (lane & 15)) * LDKF + col];
            #pragma unroll
            for (int n = 0; n < 4; ++n)
                bfr[n] = *(const bf16x8*)&sB[(wc + n * 16 + (lane & 15)) * LDKF + col];
            #pragma unroll
            for (int m = 0; m < 4; ++m)
                #pragma unroll
                for (int n = 0; n < 4; ++n)
                    acc[m][n] = __builtin_amdgcn_mfma_f32_16x16x32_bf16(
                        af[m], bfr[n], acc[m][n], 0, 0, 0);
        }
        __syncthreads();
    }
    float* Cp = C + (size_t)(bm + wr) * NN + bn + wc;
    const int cr = (lane >> 4) << 2, cc = lane & 15;
    #pragma unroll
    for (int m = 0; m < 4; ++m)
        #pragma unroll
        for (int j = 0; j < 4; ++j) {
            float* dst = Cp + (size_t)(m * 16 + cr + j) * NN + cc;
            #pragma unroll
            for (int n = 0; n < 4; ++n) dst[n * 16] = acc[m][n][j];
        }
}

extern "C" void kernel_launch(void* const* d_in, const int* in_sizes, int n_in,
                              void* d_out, int out_size, void* d_ws, size_t ws_size,
                              hipStream_t stream) {
    const float* A  = (const float*)d_in[0];
    const int*   W  = (const int*)d_in[1];
    const float* SZ = (const float*)d_in[2];
    float* C = (float*)d_out;

    const int M = in_sizes[0] / KK;   // 2048

    const size_t ab_elems = (size_t)M * KK;
    const size_t need = ab_elems * sizeof(short);   // 16 MB

    if (ws_size >= need && (M % 256) == 0) {
        short* Ab = (short*)d_ws;
        cvt_a<<<(int)(ab_elems / 8 / 256), 256, 0, stream>>>(A, Ab);
        dim3 grid(NN / 128, M / 256);
        gemm_fq<<<grid, dim3(512), 0, stream>>>(Ab, W, SZ, C);
    } else {
        dim3 grid(NN / 128, M / 128);
        wq4_gemm_fused<<<grid, dim3(256), 0, stream>>>(A, W, SZ, C, M);
    }
}

// Round 10
// 99.189 us; speedup vs baseline: 1.0485x; 1.0485x over previous
//
#include <hip/hip_runtime.h>
#include <hip/hip_bf16.h>

// Weight-only int4 GEMM (M=2048, N=4096, K=4096, G=128):
//   1) cvt_a    : fp32 A -> bf16 Ab[M][K] in d_ws (only prepass)
//   2) gemm_fq2 : R5 pipelined bf16 GEMM (BM=256 x BN=128, BK=64, 8 waves of
//        64x64, mfma_f32_32x32x16_bf16, ONE barrier/K-tile, 3-deep LDS ring)
//        with W-dequant fused into B staging. Packed-W regs are prefetched
//        ONE FULL K-TILE early (loads for t+3 issued in tile t, consumed in
//        tile t+1) via even/odd named register sets (loop unrolled x2, no
//        dynamic reg copies). vmcnt audit: per tile 4 A-gloads (pre) +
//        3 B/sz loads (post); mid-wait vmcnt(4) drains only >=1-tile-old.

using bf16x8 = __attribute__((ext_vector_type(8))) short;
using f32x16 = __attribute__((ext_vector_type(16))) float;

#define KK 4096
#define NN 4096
#define NT (KK / 64)

static __device__ __forceinline__ short f2bf(float f) {
    __hip_bfloat16 h = __float2bfloat16(f);
    return __builtin_bit_cast(short, h);
}

#define GLDS16(gptr, lptr) __builtin_amdgcn_global_load_lds( \
    (const __attribute__((address_space(1))) void*)(gptr),   \
    (__attribute__((address_space(3))) void*)(lptr), 16, 0, 0)

#define MFMA32 __builtin_amdgcn_mfma_f32_32x32x16_bf16
#define SBAR() __builtin_amdgcn_sched_barrier(0)

static __device__ __forceinline__ bf16x8 dq8(int4 p, float s, float zs) {
    bf16x8 r;
    int v[4] = {p.x, p.y, p.z, p.w};
    #pragma unroll
    for (int j = 0; j < 4; ++j) {
        r[2 * j]     = f2bf((float)((v[j] >> 4) & 0xF) * s + zs); // even k
        r[2 * j + 1] = f2bf((float)(v[j] & 0xF) * s + zs);        // odd k
    }
    return r;
}

// ---------------- pre-pass: A fp32 -> bf16 ----------------
__global__ __launch_bounds__(256) void cvt_a(
    const float* __restrict__ A, short* __restrict__ Ab)
{
    const int idx = blockIdx.x * 256 + threadIdx.x;
    const float4* s = (const float4*)(A + (size_t)idx * 8);
    float4 u = s[0], v = s[1];
    bf16x8 r;
    r[0] = f2bf(u.x); r[1] = f2bf(u.y); r[2] = f2bf(u.z); r[3] = f2bf(u.w);
    r[4] = f2bf(v.x); r[5] = f2bf(v.y); r[6] = f2bf(v.z); r[7] = f2bf(v.w);
    *(bf16x8*)&Ab[(size_t)idx * 8] = r;
}

// ---------------- main pipelined GEMM, fused W-dequant ----------------
// LDS(row, chunk c) holds global(row, c ^ (row&7)); chunks are 16B.
__global__ __launch_bounds__(512, 2) void gemm_fq2(
    const short* __restrict__ Ab, const int* __restrict__ W,
    const float* __restrict__ SZ, float* __restrict__ C)
{
    __shared__ short sA[3 * 256 * 64];   // 96 KiB
    __shared__ short sB[3 * 128 * 64];   // 48 KiB

    const int tid  = threadIdx.x;
    const int lane = tid & 63;
    const int wave = tid >> 6;           // 0..7
    const int wm   = wave >> 1;          // m-offset wm*64 (0..3)
    const int wn   = wave & 1;           // n-offset wn*64
    const int bm   = blockIdx.y * 256;
    const int bn   = blockIdx.x * 128;

    // A staging via gload_lds: wave fills 8 rows x 8 chunks linearly;
    // global source pre-swizzled: row += lane>>3, chunk (lane&7)^(lane>>3)
    const int sl = lane >> 3;
    const int sc = (lane & 7) ^ sl;
    const short* aSt = Ab + (size_t)(bm + wave * 32 + sl) * KK + sc * 8;

    // B staging: reg-staged packed int4 + dequant.
    // Per lane: tile-row brow = wave*16 + (lane>>2); 8 int32 = 16 k-elems;
    // two swizzled ds_write_b128 (2-way bank aliasing per beat = free).
    const int brow = wave * 16 + (lane >> 2);
    const int bl4  = lane & 3;
    const int* wSt = W + (size_t)(bn + brow) * (KK / 2) + bl4 * 8;
    const float* szp = SZ + (size_t)(bn + brow) * 2;
    const int bw0 = brow * 64 + (((bl4 * 2))     ^ (brow & 7)) * 8;
    const int bw1 = brow * 64 + (((bl4 * 2) | 1) ^ (brow & 7)) * 8;

    // 32x32x16 fragment reads: row = base + (lane&31);
    // logical chunk = slice*2 + (lane>>5); phys = logical ^ (lane&7)
    const int l31 = lane & 31;
    const int lx  = lane >> 5;
    const int l7  = lane & 7;
    const int px0 = ((0 + lx) ^ l7) * 8;   // k-slice 0
    const int px1 = ((2 + lx) ^ l7) * 8;   // k-slice 1
    const int px2 = ((4 + lx) ^ l7) * 8;   // k-slice 2
    const int px3 = ((6 + lx) ^ l7) * 8;   // k-slice 3
    const int aRd = (wm * 64 + l31) * 64;
    const int bRd = (wn * 64 + l31) * 64;

    f32x16 acc00 = {}, acc01 = {}, acc10 = {}, acc11 = {};
    bf16x8 pA00, pA01, pA10, pA11, pB00, pB01, pB10, pB11;  // phase-0 frags
    bf16x8 qA00, qA01, qA10, qA11, qB00, qB01, qB10, qB11;  // phase-1 frags
    int4 bpE0, bpE1, bpO0, bpO1; float2 szE, szO;           // even/odd W regs

    // ---- prologue ----
    // vm issue order: w0/w1/sz01 (5), A0 x4, A1 x4, bpE(tile2) + szE (3)
    int4 w0a = *(const int4*)(wSt + 0);
    int4 w0b = *(const int4*)(wSt + 4);
    int4 w1a = *(const int4*)(wSt + 32);
    int4 w1b = *(const int4*)(wSt + 36);
    float2 sz01 = *(const float2*)(szp);                 // group 0
    #pragma unroll
    for (int l = 0; l < 4; ++l)
        GLDS16(aSt + (size_t)l * 8 * KK,      &sA[(wave * 32 + l * 8) * 64]);
    #pragma unroll
    for (int l = 0; l < 4; ++l)
        GLDS16(aSt + (size_t)l * 8 * KK + 64, &sA[16384 + (wave * 32 + l * 8) * 64]);
    bpE0 = *(const int4*)(wSt + 64);                     // tile 2
    bpE1 = *(const int4*)(wSt + 68);
    szE  = *(const float2*)(szp + (size_t)NN * 2);       // group 1
    {
        const float s = sz01.x, zs = sz01.y - 8.0f * sz01.x;
        *(bf16x8*)&sB[bw0]        = dq8(w0a, s, zs);     // tile 0
        *(bf16x8*)&sB[bw1]        = dq8(w0b, s, zs);
        *(bf16x8*)&sB[8192 + bw0] = dq8(w1a, s, zs);     // tile 1
        *(bf16x8*)&sB[8192 + bw1] = dq8(w1b, s, zs);
    }
    asm volatile("s_waitcnt vmcnt(7)" ::: "memory");     // A0 landed
    asm volatile("s_waitcnt lgkmcnt(0)" ::: "memory");   // B0/B1 written
    __builtin_amdgcn_s_barrier();

    // first p-set of tile 0 (slices 0,1)
    pA00 = *(const bf16x8*)&sA[aRd + px0];
    pA01 = *(const bf16x8*)&sA[aRd + px1];
    pA10 = *(const bf16x8*)&sA[aRd + 2048 + px0];
    pA11 = *(const bf16x8*)&sA[aRd + 2048 + px1];
    pB00 = *(const bf16x8*)&sB[bRd + px0];
    pB01 = *(const bf16x8*)&sB[bRd + px1];
    pB10 = *(const bf16x8*)&sB[bRd + 2048 + px0];
    pB11 = *(const bf16x8*)&sB[bRd + 2048 + px1];
    asm volatile("s_waitcnt lgkmcnt(0)" ::: "memory");
    SBAR();

    int cur = 0;

    // TILE_BODY(T): write B(T+2) from BPW regs (loaded at T-1, or prologue);
    //               load BPL regs for tile T+3.
#define TILE_BODY(T, BPW0, BPW1, SZW, BPL0, BPL1, SZL)                        \
    {                                                                         \
        const int nxt1 = (cur == 2) ? 0 : cur + 1;                            \
        const int nxt2 = (nxt1 == 2) ? 0 : nxt1 + 1;                          \
        const short* sAc = &sA[cur * 16384];                                  \
        const short* sBc = &sB[cur * 8192];                                   \
        const short* sA1 = &sA[nxt1 * 16384];                                 \
        const short* sB1 = &sB[nxt1 * 8192];                                  \
        short* sAn = &sA[nxt2 * 16384];                                       \
        short* sBn = &sB[nxt2 * 8192];                                        \
        const bool st = ((T) + 2 < NT);                                       \
        const int gk = ((T) + 2) * 64;                                        \
        /* pre: q-frag reads + A staging for T+2 */                           \
        qA00 = *(const bf16x8*)&sAc[aRd + px2];                               \
        qA01 = *(const bf16x8*)&sAc[aRd + px3];                               \
        qA10 = *(const bf16x8*)&sAc[aRd + 2048 + px2];                        \
        qA11 = *(const bf16x8*)&sAc[aRd + 2048 + px3];                        \
        qB00 = *(const bf16x8*)&sBc[bRd + px2];                               \
        qB01 = *(const bf16x8*)&sBc[bRd + px3];                               \
        qB10 = *(const bf16x8*)&sBc[bRd + 2048 + px2];                        \
        qB11 = *(const bf16x8*)&sBc[bRd + 2048 + px3];                        \
        if (st) {                                                             \
            GLDS16(aSt + (size_t)0 * 8 * KK + gk, sAn + (wave * 32 + 0) * 64);\
            GLDS16(aSt + (size_t)1 * 8 * KK + gk, sAn + (wave * 32 + 8) * 64);\
            GLDS16(aSt + (size_t)2 * 8 * KK + gk, sAn + (wave * 32 + 16) * 64);\
            GLDS16(aSt + (size_t)3 * 8 * KK + gk, sAn + (wave * 32 + 24) * 64);\
        }                                                                     \
        SBAR();                                                               \
        __builtin_amdgcn_s_setprio(1);                                        \
        acc00 = MFMA32(pA00, pB00, acc00, 0, 0, 0);                           \
        acc00 = MFMA32(pA01, pB01, acc00, 0, 0, 0);                           \
        acc01 = MFMA32(pA00, pB10, acc01, 0, 0, 0);                           \
        acc01 = MFMA32(pA01, pB11, acc01, 0, 0, 0);                           \
        acc10 = MFMA32(pA10, pB00, acc10, 0, 0, 0);                           \
        acc10 = MFMA32(pA11, pB01, acc10, 0, 0, 0);                           \
        acc11 = MFMA32(pA10, pB10, acc11, 0, 0, 0);                           \
        acc11 = MFMA32(pA11, pB11, acc11, 0, 0, 0);                           \
        __builtin_amdgcn_s_setprio(0);                                        \
        /* mid: drain >=1-tile-old vmem; single barrier */                    \
        asm volatile("s_waitcnt lgkmcnt(0)" ::: "memory");                    \
        SBAR();                                                               \
        if (st) {                                                             \
            asm volatile("s_waitcnt vmcnt(4)" ::: "memory");                  \
        } else {                                                              \
            asm volatile("s_waitcnt vmcnt(0)" ::: "memory");                  \
        }                                                                     \
        __builtin_amdgcn_s_barrier();                                         \
        /* post: next p-frags, B loads for T+3, B write for T+2 */            \
        if ((T) + 1 < NT) {                                                   \
            pA00 = *(const bf16x8*)&sA1[aRd + px0];                           \
            pA01 = *(const bf16x8*)&sA1[aRd + px1];                           \
            pA10 = *(const bf16x8*)&sA1[aRd + 2048 + px0];                    \
            pA11 = *(const bf16x8*)&sA1[aRd + 2048 + px1];                    \
            pB00 = *(const bf16x8*)&sB1[bRd + px0];                           \
            pB01 = *(const bf16x8*)&sB1[bRd + px1];                           \
            pB10 = *(const bf16x8*)&sB1[bRd + 2048 + px0];                    \
            pB11 = *(const bf16x8*)&sB1[bRd + 2048 + px1];                    \
        }                                                                     \
        if ((T) + 3 < NT) {                                                   \
            BPL0 = *(const int4*)(wSt + (((T) + 3) * 32));                    \
            BPL1 = *(const int4*)(wSt + (((T) + 3) * 32) + 4);                \
            SZL  = *(const float2*)(szp + (size_t)(((T) + 3) >> 1) * NN * 2); \
        }                                                                     \
        if (st) {                                                             \
            const float s = SZW.x, zs = SZW.y - 8.0f * SZW.x;                 \
            *(bf16x8*)&sBn[bw0] = dq8(BPW0, s, zs);                           \
            *(bf16x8*)&sBn[bw1] = dq8(BPW1, s, zs);                           \
        }                                                                     \
        SBAR();                                                               \
        __builtin_amdgcn_s_setprio(1);                                        \
        acc00 = MFMA32(qA00, qB00, acc00, 0, 0, 0);                           \
        acc00 = MFMA32(qA01, qB01, acc00, 0, 0, 0);                           \
        acc01 = MFMA32(qA00, qB10, acc01, 0, 0, 0);                           \
        acc01 = MFMA32(qA01, qB11, acc01, 0, 0, 0);                           \
        acc10 = MFMA32(qA10, qB00, acc10, 0, 0, 0);                           \
        acc10 = MFMA32(qA11, qB01, acc10, 0, 0, 0);                           \
        acc11 = MFMA32(qA10, qB10, acc11, 0, 0, 0);                           \
        acc11 = MFMA32(qA11, qB11, acc11, 0, 0, 0);                           \
        __builtin_amdgcn_s_setprio(0);                                        \
        asm volatile("s_waitcnt lgkmcnt(0)" ::: "memory");                    \
        SBAR();                                                               \
        cur = nxt1;                                                           \
    }

    for (int t = 0; t < NT; t += 2) {
        TILE_BODY(t,     bpE0, bpE1, szE, bpO0, bpO1, szO);   // even
        TILE_BODY(t + 1, bpO0, bpO1, szO, bpE0, bpE1, szE);   // odd
    }
#undef TILE_BODY

    // ---- epilogue: 32x32 C/D layout: col = lane&31,
    //      row = (reg&3) + 8*(reg>>2) + 4*(lane>>5) ----
    {
        const int crow = lx * 4;
        float* Cp = C + (size_t)(bm + wm * 64) * NN + bn + wn * 64;
        #pragma unroll
        for (int m = 0; m < 2; ++m) {
            #pragma unroll
            for (int qr = 0; qr < 4; ++qr) {
                #pragma unroll
                for (int j = 0; j < 4; ++j) {
                    const int row = m * 32 + crow + j + 8 * qr;
                    float* dst = Cp + (size_t)row * NN + l31;
                    if (m == 0) {
                        dst[0]  = acc00[qr * 4 + j];
                        dst[32] = acc01[qr * 4 + j];
                    } else {
                        dst[0]  = acc10[qr * 4 + j];
                        dst[32] = acc11[qr * 4 + j];
                    }
                }
            }
        }
    }
}

// ---------------- fallback: round-1 fused kernel ----------------
using f32x4 = __attribute__((ext_vector_type(4))) float;
#define LDKF 72
__global__ __launch_bounds__(256) void wq4_gemm_fused(
    const float* __restrict__ A, const int* __restrict__ W,
    const float* __restrict__ SZ, float* __restrict__ C, int M)
{
    __shared__ short sA[128 * LDKF];
    __shared__ short sB[128 * LDKF];
    const int tid = threadIdx.x, lane = tid & 63, wave = tid >> 6;
    const int wr = (wave >> 1) << 6, wc = (wave & 1) << 6;
    const int bm = blockIdx.y * 128, bn = blockIdx.x * 128;
    const int ar = tid >> 2, ac = (tid & 3) << 4;
    const int br = tid >> 1, bh = (tid & 1) << 4;
    const float* Arow0 = A + (size_t)(bm + ar) * KK + ac;
    const float* Arow1 = A + (size_t)(bm + 64 + ar) * KK + ac;
    const int*   Wrow  = W + (size_t)(bn + br) * (KK / 2) + bh;
    const float* SZrow = SZ + (size_t)(bn + br) * 2;
    f32x4 acc[4][4] = {};
    for (int k0 = 0; k0 < KK; k0 += 64) {
        {
            const float4* s0 = (const float4*)(Arow0 + k0);
            const float4* s1 = (const float4*)(Arow1 + k0);
            float4 a0 = s0[0], a1 = s0[1], a2 = s0[2], a3 = s0[3];
            float4 b0 = s1[0], b1 = s1[1], b2 = s1[2], b3 = s1[3];
            auto cvt8 = [](float4 u, float4 v) -> bf16x8 {
                bf16x8 r;
                r[0] = f2bf(u.x); r[1] = f2bf(u.y); r[2] = f2bf(u.z); r[3] = f2bf(u.w);
                r[4] = f2bf(v.x); r[5] = f2bf(v.y); r[6] = f2bf(v.z); r[7] = f2bf(v.w);
                return r;
            };
            *(bf16x8*)&sA[ar * LDKF + ac]            = cvt8(a0, a1);
            *(bf16x8*)&sA[ar * LDKF + ac + 8]        = cvt8(a2, a3);
            *(bf16x8*)&sA[(64 + ar) * LDKF + ac]     = cvt8(b0, b1);
            *(bf16x8*)&sA[(64 + ar) * LDKF + ac + 8] = cvt8(b2, b3);
        }
        {
            const int g = k0 >> 7;
            const float2 sz = *(const float2*)(SZrow + (size_t)g * NN * 2);
            const float scale = sz.x, zs = sz.y - 8.0f * sz.x;
            const int4* src = (const int4*)(Wrow + (k0 >> 1));
            #pragma unroll
            for (int i = 0; i < 4; ++i) {
                int4 p = src[i];
                int vals[4] = {p.x, p.y, p.z, p.w};
                bf16x8 r;
                #pragma unroll
                for (int j = 0; j < 4; ++j) {
                    int v = vals[j];
                    r[2 * j]     = f2bf((float)((v >> 4) & 0xF) * scale + zs);
                    r[2 * j + 1] = f2bf((float)(v & 0xF) * scale + zs);
                }
                *(bf16x8*)&sB[br * LDKF + (bh << 1) + (i << 3)] = r;
            }
        }
        __syncthreads();
        #pragma unroll
        for (int ks = 0; ks < 2; ++ks) {
            const int col = (ks << 5) + ((lane >> 4) << 3);
            bf16x8 af[4], bfr[4];
            #pragma unroll
            for (int m = 0; m < 4; ++m)
                af[m] = *(const bf16x8*)&sA[(wr + m * 16 + (lane & 15)) * LDKF + col];
            #pragma unroll
            for (int n = 0; n < 4; ++n)
                bfr[n] = *(const bf16x8*)&sB[(wc + n * 16 + (lane & 15)) * LDKF + col];
            #pragma unroll
            for (int m = 0; m < 4; ++m)
                #pragma unroll
                for (int n = 0; n < 4; ++n)
                    acc[m][n] = __builtin_amdgcn_mfma_f32_16x16x32_bf16(
                        af[m], bfr[n], acc[m][n], 0, 0, 0);
        }
        __syncthreads();
    }
    float* Cp = C + (size_t)(bm + wr) * NN + bn + wc;
    const int cr = (lane >> 4) << 2, cc = lane & 15;
    #pragma unroll
    for (int m = 0; m < 4; ++m)
        #pragma unroll
        for (int j = 0; j < 4; ++j) {
            float* dst = Cp + (size_t)(m * 16 + cr + j) * NN + cc;
            #pragma unroll
            for (int n = 0; n < 4; ++n) dst[n * 16] = acc[m][n][j];
        }
}

extern "C" void kernel_launch(void* const* d_in, const int* in_sizes, int n_in,
                              void* d_out, int out_size, void* d_ws, size_t ws_size,
                              hipStream_t stream) {
    const float* A  = (const float*)d_in[0];
    const int*   W  = (const int*)d_in[1];
    const float* SZ = (const float*)d_in[2];
    float* C = (float*)d_out;

    const int M = in_sizes[0] / KK;   // 2048

    const size_t ab_elems = (size_t)M * KK;
    const size_t need = ab_elems * sizeof(short);   // 16 MB

    if (ws_size >= need && (M % 256) == 0) {
        short* Ab = (short*)d_ws;
        cvt_a<<<(int)(ab_elems / 8 / 256), 256, 0, stream>>>(A, Ab);
        dim3 grid(NN / 128, M / 256);
        gemm_fq2<<<grid, dim3(512), 0, stream>>>(Ab, W, SZ, C);
    } else {
        dim3 grid(NN / 128, M / 128);
        wq4_gemm_fused<<<grid, dim3(256), 0, stream>>>(A, W, SZ, C, M);
    }
}